// Round 6
// baseline (4117.200 us; speedup 1.0000x reference)
//
#include <hip/hip_runtime.h>
#include <cstdint>
#include <cstddef>

// B=256, T=512, D=64, H=256, G=1024. Two-layer LSTM + FC.
// TCH=32 chunks; per iteration one fused gemm dispatch (both layers) and one
// fused rec dispatch (layer0 chunk i on blocks 0-15, layer1 chunk i-1 on 16-31).
// R6 register budget (256/wave at 8 waves/CU): W k-frags 0-1 in LDS (128 KB),
// k-frags 2-6 in wreg (160 VGPR), k-frag 7 re-loaded from L1/L2 each step as
// transients (32, die before cell phase). xp now (s,r)-major per lane: cell
// phase loads 8x8B slices JIT (no persistent xv regs). Peak ~244 regs.
#define GATES 1024
#define SEQT  512
#define TCH   32
#define NCH   16
#define XPSTEP 262144   // elements per timestep in rec-order xp: 16*512*32

using u16 = unsigned short;
using bf16x8 = __attribute__((ext_vector_type(8))) short;   // 8 bf16 = 4 VGPRs
using bf16x4 = __attribute__((ext_vector_type(4))) short;   // 4 bf16 = 2 VGPRs
using f32x4  = __attribute__((ext_vector_type(4))) float;

__device__ __forceinline__ float bf2f(u16 u) {
    union { float f; unsigned int i; } v; v.i = ((unsigned int)u) << 16; return v.f;
}
__device__ __forceinline__ u16 f2bf(float f) {
    union { float f; unsigned int i; } v; v.f = f;
    unsigned int r = v.i + 0x7FFFu + ((v.i >> 16) & 1u);   // RNE
    return (u16)(r >> 16);
}
// overflow-safe fast activations (v_exp + v_rcp, ~1 ulp)
__device__ __forceinline__ float sigm(float x) {
    return __builtin_amdgcn_rcpf(1.f + __expf(-x));
}
__device__ __forceinline__ float tanh_f(float x) {
    return 1.f - 2.f * __builtin_amdgcn_rcpf(1.f + __expf(2.f * x));
}

// ---------------- prep ----------------
__global__ void k_conv(const float* __restrict__ src, u16* __restrict__ dst, int n) {
    int i = blockIdx.x * 256 + threadIdx.x;
    if (i < n) dst[i] = f2bf(src[i]);
}
__global__ void k_bias(const float* __restrict__ a, const float* __restrict__ b,
                       float* __restrict__ o, int n) {
    int i = blockIdx.x * 256 + threadIdx.x;
    if (i < n) o[i] = a[i] + b[i];
}

// ---------------- fused input-projection GEMM ----------------
// blocks 0-511: layer0 (A=xb [256][512][64], K=64); 512-1023: layer1 (A=h0c).
// Scatter to rec-order, (s,r)-major micro-layout:
//   el = ((tloc*16+blk)*512 + w*64 + qr*16 + mlr)*32 + (s*4 + r_r)*4 + gi
__global__ __launch_bounds__(256, 2) void gemm_fused(
    const u16* __restrict__ A0, const u16* __restrict__ W0,
    const float* __restrict__ b0, u16* __restrict__ o0, int t00,
    const u16* __restrict__ A1, const u16* __restrict__ W1,
    const float* __restrict__ b1, u16* __restrict__ o1, int it)
{
    const int half = blockIdx.x >> 9;
    if (half == 0 && it >= NCH) return;
    if (half == 1 && it == 0) return;
    const int bid = blockIdx.x & 511;

    const u16* A; const u16* W; const float* bias; u16* out;
    int K, As_b, As_t, t0;
    if (half == 0) { A = A0; W = W0; bias = b0; out = o0; K = 64;  As_b = 32768; As_t = 64;    t0 = t00; }
    else           { A = A1; W = W1; bias = b1; out = o1; K = 256; As_b = 256;   As_t = 65536; t0 = 0;   }

    __shared__ __align__(16) u16 As[128][40];
    __shared__ __align__(16) u16 Bs[128][40];
    const int tid  = threadIdx.x;
    const int mb   = bid >> 3, nb = bid & 7;
    const int n0   = nb * 128;
    const int wave = tid >> 6, lane = tid & 63;
    const int wm   = wave >> 1, wn = wave & 1;
    const int ml   = lane & 15, q = lane >> 4;
    const int tloc = mb >> 1;
    const int tt   = t0 + tloc;
    const int bbas = (mb & 1) * 128;

    f32x4 acc[4][4];
    #pragma unroll
    for (int mi = 0; mi < 4; ++mi)
        #pragma unroll
        for (int ni = 0; ni < 4; ++ni)
            acc[mi][ni] = (f32x4)0.f;

    const int nk = K >> 5;
    for (int kt = 0; kt < nk; ++kt) {
        __syncthreads();
        #pragma unroll
        for (int i = 0; i < 2; ++i) {
            int c = tid + i * 256;
            int row = c >> 2, kb = c & 3;
            *(uint4*)&As[row][kb * 8] = *(const uint4*)(
                A + (size_t)(bbas + row) * As_b + (size_t)tt * As_t + kt * 32 + kb * 8);
            *(uint4*)&Bs[row][kb * 8] = *(const uint4*)(
                W + (size_t)(n0 + row) * K + kt * 32 + kb * 8);
        }
        __syncthreads();
        bf16x8 af[4], bfr[4];
        #pragma unroll
        for (int mi = 0; mi < 4; ++mi)
            af[mi] = *(const bf16x8*)&As[wm * 64 + mi * 16 + ml][q * 8];
        #pragma unroll
        for (int ni = 0; ni < 4; ++ni)
            bfr[ni] = *(const bf16x8*)&Bs[wn * 64 + ni * 16 + ml][q * 8];
        #pragma unroll
        for (int mi = 0; mi < 4; ++mi)
            #pragma unroll
            for (int ni = 0; ni < 4; ++ni)
                acc[mi][ni] = __builtin_amdgcn_mfma_f32_16x16x32_bf16(
                    af[mi], bfr[ni], acc[mi][ni], 0, 0, 0);
    }

    #pragma unroll
    for (int ni = 0; ni < 4; ++ni) {
        int gc = n0 + wn * 64 + ni * 16 + ml;
        int gi = gc >> 8, u = gc & 255;
        int w = u >> 5, s = (u >> 4) & 1, mlr = u & 15;
        float bv = bias[gc];
        #pragma unroll
        for (int mi = 0; mi < 4; ++mi) {
            int b0r = bbas + wm * 64 + mi * 16 + q * 4;
            #pragma unroll
            for (int rr = 0; rr < 4; ++rr) {
                int bb = b0r + rr;
                int blk = bb >> 4, qr = (bb >> 2) & 3, r_r = bb & 3;
                size_t el = ((size_t)((tloc * 16 + blk) * 512 + w * 64 + qr * 16 + mlr)) * 32
                            + (s * 4 + r_r) * 4 + gi;
                out[el] = f2bf(acc[mi][ni][rr] + bv);
            }
        }
    }
}

// ---------------- fused LSTM recurrence ----------------
// Blocks 0-15: layer0 chunk it; 16-31: layer1 chunk it-1. Wave owns 128 gate
// rows. W: kf0-1 LDS (staged once), kf2-6 wreg (160 VGPR), kf7 global b128
// per step (transient). hA double-buffered, one barrier/step. xp loaded JIT
// in the cell phase as 8x8B slices ((s,r)-major layout).
__global__ __launch_bounds__(512, 2) void lstm_rec2(
    const u16* __restrict__ xp0, const u16* __restrict__ xp1,
    const u16* __restrict__ W0,  const u16* __restrict__ W1,
    u16* __restrict__ h0c, float* __restrict__ hlast,
    u16* __restrict__ hs0, float* __restrict__ cs0,
    u16* __restrict__ hs1, float* __restrict__ cs1, int it)
{
    const int L   = blockIdx.x >> 4;
    const int blk = blockIdx.x & 15;
    if (L == 0 && it >= NCH) return;
    if (L == 1 && it == 0) return;
    const int chunk = L ? it - 1 : it;
    const u16* xp = L ? xp1 : xp0;
    const u16* W  = L ? W1 : W0;
    u16*  hs = L ? hs1 : hs0;
    float* cs = L ? cs1 : cs0;
    const int init = (chunk == 0);

    __shared__ __align__(16) u16 WL[8 * 16 * 64 * 8];   // 131072 B: kf0-1, frag-order
    __shared__ __align__(16) u16 hA[2][16][264];        // 16896 B, double buffer

    const int tid  = threadIdx.x;
    const int wave = tid >> 6, lane = tid & 63;
    const int ml   = lane & 15, q = lane >> 4;
    const int ub   = wave * 32;
    const int bb0  = blk * 16;

    // W fragment element offsets: frag f = gi*2+s -> gate rows g
    int woff_[8];
    #pragma unroll
    for (int gi = 0; gi < 4; ++gi)
        #pragma unroll
        for (int s = 0; s < 2; ++s)
            woff_[gi * 2 + s] = (gi * 256 + ub + s * 16 + ml) * 256 + q * 8;

    // stage kf0-1 into LDS (lane round-trips its own 16 B)
    const int wlb = (wave * 1024 + lane) * 8;
    #pragma unroll
    for (int kf = 0; kf < 2; ++kf)
        #pragma unroll
        for (int f = 0; f < 8; ++f)
            *(bf16x8*)&WL[wlb + (kf * 8 + f) * 512] =
                *(const bf16x8*)(W + woff_[f] + kf * 32);

    // kf2-6 persistent registers (160 VGPR)
    bf16x8 wreg[5][8];
    #pragma unroll
    for (int kf = 2; kf < 7; ++kf)
        #pragma unroll
        for (int f = 0; f < 8; ++f)
            wreg[kf - 2][f] = *(const bf16x8*)(W + woff_[f] + kf * 32);

    float c_[8];
    if (init) {
        for (int i = tid; i < 16 * 264; i += 512) ((u16*)&hA[0][0][0])[i] = 0;
        #pragma unroll
        for (int i = 0; i < 8; ++i) c_[i] = 0.f;
    } else {
        int m = tid >> 5, j0 = (tid & 31) * 8;
        *(bf16x8*)&hA[0][m][j0] = *(const bf16x8*)&hs[(size_t)(bb0 + m) * 256 + j0];
        #pragma unroll
        for (int s = 0; s < 2; ++s)
            #pragma unroll
            for (int r = 0; r < 4; ++r)
                c_[s * 4 + r] = cs[(size_t)(bb0 + q * 4 + r) * 256 + ub + s * 16 + ml];
    }

    const u16* xpt = xp + ((size_t)blk * 512 + tid) * 32;   // advance XPSTEP/step

    __syncthreads();

    for (int t = 0; t < TCH; ++t) {
        const int br = t & 1, bw = br ^ 1;

        // kf7 B-frags: transient, from L1/L2 (same addresses every step)
        bf16x8 wk7[8];
        #pragma unroll
        for (int f = 0; f < 8; ++f)
            wk7[f] = *(const bf16x8*)(W + woff_[f] + 7 * 32);

        f32x4 acc[4][2];
        #pragma unroll
        for (int gi = 0; gi < 4; ++gi)
            #pragma unroll
            for (int s = 0; s < 2; ++s)
                acc[gi][s] = (f32x4)0.f;

        // kf0-1 from LDS
        #pragma unroll
        for (int kf = 0; kf < 2; ++kf) {
            bf16x8 a = *(const bf16x8*)&hA[br][ml][kf * 32 + q * 8];
            #pragma unroll
            for (int f = 0; f < 8; ++f) {
                bf16x8 b = *(const bf16x8*)&WL[wlb + (kf * 8 + f) * 512];
                acc[f >> 1][f & 1] = __builtin_amdgcn_mfma_f32_16x16x32_bf16(
                    a, b, acc[f >> 1][f & 1], 0, 0, 0);
            }
        }
        // kf2-6 from persistent registers
        #pragma unroll
        for (int kf = 2; kf < 7; ++kf) {
            bf16x8 a = *(const bf16x8*)&hA[br][ml][kf * 32 + q * 8];
            #pragma unroll
            for (int f = 0; f < 8; ++f)
                acc[f >> 1][f & 1] = __builtin_amdgcn_mfma_f32_16x16x32_bf16(
                    a, wreg[kf - 2][f], acc[f >> 1][f & 1], 0, 0, 0);
        }
        // kf7 from transients
        {
            bf16x8 a = *(const bf16x8*)&hA[br][ml][7 * 32 + q * 8];
            #pragma unroll
            for (int f = 0; f < 8; ++f)
                acc[f >> 1][f & 1] = __builtin_amdgcn_mfma_f32_16x16x32_bf16(
                    a, wk7[f], acc[f >> 1][f & 1], 0, 0, 0);
        }

        // cell phase: xp slices loaded JIT ((s,r)-major, 8 B each)
        #pragma unroll
        for (int s = 0; s < 2; ++s) {
            int j = ub + s * 16 + ml;
            #pragma unroll
            for (int r = 0; r < 4; ++r) {
                int m = q * 4 + r;
                bf16x4 xq = *(const bf16x4*)(xpt + (s * 4 + r) * 4);
                float ig = sigm(acc[0][s][r] + bf2f((u16)xq[0]));
                float fg = sigm(acc[1][s][r] + bf2f((u16)xq[1]));
                float gg = tanh_f(acc[2][s][r] + bf2f((u16)xq[2]));
                float og = sigm(acc[3][s][r] + bf2f((u16)xq[3]));
                float cc = fg * c_[s * 4 + r] + ig * gg;
                c_[s * 4 + r] = cc;
                float h = og * tanh_f(cc);
                u16 hb = f2bf(h);
                hA[bw][m][j] = hb;
                if (L == 0)
                    h0c[((size_t)t * 256 + bb0 + m) * 256 + j] = hb;
                else if (chunk == NCH - 1 && t == TCH - 1)
                    hlast[(size_t)(bb0 + m) * 256 + j] = h;
            }
        }
        xpt += XPSTEP;
        __syncthreads();   // h(t+1) published in buf bw
    }

    // persist state (TCH even -> final h in buf 0)
    #pragma unroll
    for (int s = 0; s < 2; ++s)
        #pragma unroll
        for (int r = 0; r < 4; ++r)
            cs[(size_t)(bb0 + q * 4 + r) * 256 + ub + s * 16 + ml] = c_[s * 4 + r];
    {
        int m = tid >> 5, j0 = (tid & 31) * 8;
        *(bf16x8*)&hs[(size_t)(bb0 + m) * 256 + j0] = *(const bf16x8*)&hA[0][m][j0];
    }
}

// ---------------- FC head ----------------
__global__ void fc_k(const float* __restrict__ h, const float* __restrict__ w,
                     const float* __restrict__ b, float* __restrict__ out)
{
    int bb = blockIdx.x, lane = threadIdx.x;
    float s = 0.f;
    for (int j = lane; j < 256; j += 64) s += h[bb * 256 + j] * w[j];
    #pragma unroll
    for (int off = 32; off > 0; off >>= 1) s += __shfl_down(s, off);
    if (lane == 0) out[bb] = s + b[0];
}

extern "C" void kernel_launch(void* const* d_in, const int* in_sizes, int n_in,
                              void* d_out, int out_size, void* d_ws, size_t ws_size,
                              hipStream_t stream)
{
    const float* x    = (const float*)d_in[0];
    const float* Wih0 = (const float*)d_in[1];
    const float* Whh0 = (const float*)d_in[2];
    const float* bih0 = (const float*)d_in[3];
    const float* bhh0 = (const float*)d_in[4];
    const float* Wih1 = (const float*)d_in[5];
    const float* Whh1 = (const float*)d_in[6];
    const float* bih1 = (const float*)d_in[7];
    const float* bhh1 = (const float*)d_in[8];
    const float* fcw  = (const float*)d_in[9];
    const float* fcb  = (const float*)d_in[10];
    float* out = (float*)d_out;

    // workspace layout, total ~57.3 MB
    char* ws = (char*)d_ws;
    u16*   xp0   = (u16*)(ws);                  // 16777216
    u16*   xp1   = (u16*)(ws + 16777216);       // 16777216
    u16*   h0c   = (u16*)(ws + 33554432);       //  4194304  [32][256][256] bf16
    u16*   xb    = (u16*)(ws + 37748736);       // 16777216  [256][512][64] bf16
    u16*   Wih0b = (u16*)(ws + 54525952);       //   131072
    u16*   Whh0b = (u16*)(ws + 54657024);       //   524288
    u16*   Wih1b = (u16*)(ws + 55181312);       //   524288
    u16*   Whh1b = (u16*)(ws + 55705600);       //   524288
    float* bias0 = (float*)(ws + 56229888);     //     4096
    float* bias1 = (float*)(ws + 56233984);     //     4096
    u16*   hs0   = (u16*)(ws + 56238080);       //   131072
    float* cs0   = (float*)(ws + 56369152);     //   262144
    u16*   hs1   = (u16*)(ws + 56631296);       //   131072
    float* cs1   = (float*)(ws + 56762368);     //   262144
    float* h1l   = (float*)(ws + 57024512);     //   262144

    k_conv<<<32768, 256, 0, stream>>>(x, xb, 8388608);
    k_conv<<<256,   256, 0, stream>>>(Wih0, Wih0b, 65536);
    k_conv<<<1024,  256, 0, stream>>>(Whh0, Whh0b, 262144);
    k_conv<<<1024,  256, 0, stream>>>(Wih1, Wih1b, 262144);
    k_conv<<<1024,  256, 0, stream>>>(Whh1, Whh1b, 262144);
    k_bias<<<4, 256, 0, stream>>>(bih0, bhh0, bias0, 1024);
    k_bias<<<4, 256, 0, stream>>>(bih1, bhh1, bias1, 1024);

    for (int it = 0; it <= NCH; ++it) {
        gemm_fused<<<1024, 256, 0, stream>>>(xb, Wih0b, bias0, xp0, it * TCH,
                                             h0c, Wih1b, bias1, xp1, it);
        lstm_rec2<<<32, 512, 0, stream>>>(xp0, xp1, Whh0b, Whh1b, h0c, h1l,
                                          hs0, cs0, hs1, cs1, it);
    }
    fc_k<<<256, 64, 0, stream>>>(h1l, fcw, fcb, out);
}

// Round 7
// 3729.797 us; speedup vs baseline: 1.1039x; 1.1039x over previous
//
#include <hip/hip_runtime.h>
#include <cstdint>
#include <cstddef>

// B=256, T=512, D=64, H=256, G=1024. Two-layer LSTM + FC.
// TCH=32 chunks; per iteration one fused gemm dispatch (both layers) and one
// fused rec dispatch (layer0 chunk i on blocks 0-15, layer1 chunk i-1 on 16-31).
// R7: fit the 128 arch-VGPR/wave budget exactly (512-thr blocks -> 256 unified
// regs/wave = 128 V + 128 A; >128 V demand caused the R5/R6 AGPR-shuffle storm).
// W mix: kf0-1 in LDS (128 KB); kf2-7 STREAMED from L2 each step via a depth-2
// two-slot register pipeline (64 transient VGPRs). acc lives in AGPRs as MFMA
// C/D. xp preloaded at step top (4x bf16x8 = 16 regs), consumed in cell phase.
#define GATES 1024
#define SEQT  512
#define TCH   32
#define NCH   16
#define XPSTEP 262144   // elements per timestep in rec-order xp: 16*512*32

using u16 = unsigned short;
using bf16x8 = __attribute__((ext_vector_type(8))) short;   // 8 bf16 = 4 VGPRs
using bf16x4 = __attribute__((ext_vector_type(4))) short;   // 4 bf16 = 2 VGPRs
using f32x4  = __attribute__((ext_vector_type(4))) float;

__device__ __forceinline__ float bf2f(u16 u) {
    union { float f; unsigned int i; } v; v.i = ((unsigned int)u) << 16; return v.f;
}
__device__ __forceinline__ u16 f2bf(float f) {
    union { float f; unsigned int i; } v; v.f = f;
    unsigned int r = v.i + 0x7FFFu + ((v.i >> 16) & 1u);   // RNE
    return (u16)(r >> 16);
}
// overflow-safe fast activations (v_exp + v_rcp, ~1 ulp)
__device__ __forceinline__ float sigm(float x) {
    return __builtin_amdgcn_rcpf(1.f + __expf(-x));
}
__device__ __forceinline__ float tanh_f(float x) {
    return 1.f - 2.f * __builtin_amdgcn_rcpf(1.f + __expf(2.f * x));
}

// ---------------- prep ----------------
__global__ void k_conv(const float* __restrict__ src, u16* __restrict__ dst, int n) {
    int i = blockIdx.x * 256 + threadIdx.x;
    if (i < n) dst[i] = f2bf(src[i]);
}
__global__ void k_bias(const float* __restrict__ a, const float* __restrict__ b,
                       float* __restrict__ o, int n) {
    int i = blockIdx.x * 256 + threadIdx.x;
    if (i < n) o[i] = a[i] + b[i];
}

// ---------------- fused input-projection GEMM ----------------
// blocks 0-511: layer0 (A=xb [256][512][64], K=64); 512-1023: layer1 (A=h0c).
// Scatter to rec-order, (s,r)-major micro-layout:
//   el = ((tloc*16+blk)*512 + w*64 + qr*16 + mlr)*32 + (s*4 + r_r)*4 + gi
__global__ __launch_bounds__(256, 2) void gemm_fused(
    const u16* __restrict__ A0, const u16* __restrict__ W0,
    const float* __restrict__ b0, u16* __restrict__ o0, int t00,
    const u16* __restrict__ A1, const u16* __restrict__ W1,
    const float* __restrict__ b1, u16* __restrict__ o1, int it)
{
    const int half = blockIdx.x >> 9;
    if (half == 0 && it >= NCH) return;
    if (half == 1 && it == 0) return;
    const int bid = blockIdx.x & 511;

    const u16* A; const u16* W; const float* bias; u16* out;
    int K, As_b, As_t, t0;
    if (half == 0) { A = A0; W = W0; bias = b0; out = o0; K = 64;  As_b = 32768; As_t = 64;    t0 = t00; }
    else           { A = A1; W = W1; bias = b1; out = o1; K = 256; As_b = 256;   As_t = 65536; t0 = 0;   }

    __shared__ __align__(16) u16 As[128][40];
    __shared__ __align__(16) u16 Bs[128][40];
    const int tid  = threadIdx.x;
    const int mb   = bid >> 3, nb = bid & 7;
    const int n0   = nb * 128;
    const int wave = tid >> 6, lane = tid & 63;
    const int wm   = wave >> 1, wn = wave & 1;
    const int ml   = lane & 15, q = lane >> 4;
    const int tloc = mb >> 1;
    const int tt   = t0 + tloc;
    const int bbas = (mb & 1) * 128;

    f32x4 acc[4][4];
    #pragma unroll
    for (int mi = 0; mi < 4; ++mi)
        #pragma unroll
        for (int ni = 0; ni < 4; ++ni)
            acc[mi][ni] = (f32x4)0.f;

    const int nk = K >> 5;
    for (int kt = 0; kt < nk; ++kt) {
        __syncthreads();
        #pragma unroll
        for (int i = 0; i < 2; ++i) {
            int c = tid + i * 256;
            int row = c >> 2, kb = c & 3;
            *(uint4*)&As[row][kb * 8] = *(const uint4*)(
                A + (size_t)(bbas + row) * As_b + (size_t)tt * As_t + kt * 32 + kb * 8);
            *(uint4*)&Bs[row][kb * 8] = *(const uint4*)(
                W + (size_t)(n0 + row) * K + kt * 32 + kb * 8);
        }
        __syncthreads();
        bf16x8 af[4], bfr[4];
        #pragma unroll
        for (int mi = 0; mi < 4; ++mi)
            af[mi] = *(const bf16x8*)&As[wm * 64 + mi * 16 + ml][q * 8];
        #pragma unroll
        for (int ni = 0; ni < 4; ++ni)
            bfr[ni] = *(const bf16x8*)&Bs[wn * 64 + ni * 16 + ml][q * 8];
        #pragma unroll
        for (int mi = 0; mi < 4; ++mi)
            #pragma unroll
            for (int ni = 0; ni < 4; ++ni)
                acc[mi][ni] = __builtin_amdgcn_mfma_f32_16x16x32_bf16(
                    af[mi], bfr[ni], acc[mi][ni], 0, 0, 0);
    }

    #pragma unroll
    for (int ni = 0; ni < 4; ++ni) {
        int gc = n0 + wn * 64 + ni * 16 + ml;
        int gi = gc >> 8, u = gc & 255;
        int w = u >> 5, s = (u >> 4) & 1, mlr = u & 15;
        float bv = bias[gc];
        #pragma unroll
        for (int mi = 0; mi < 4; ++mi) {
            int b0r = bbas + wm * 64 + mi * 16 + q * 4;
            #pragma unroll
            for (int rr = 0; rr < 4; ++rr) {
                int bb = b0r + rr;
                int blk = bb >> 4, qr = (bb >> 2) & 3, r_r = bb & 3;
                size_t el = ((size_t)((tloc * 16 + blk) * 512 + w * 64 + qr * 16 + mlr)) * 32
                            + (s * 4 + r_r) * 4 + gi;
                out[el] = f2bf(acc[mi][ni][rr] + bv);
            }
        }
    }
}

// ---------------- fused LSTM recurrence ----------------
// Blocks 0-15: layer0 chunk it; 16-31: layer1 chunk it-1. Wave owns 128 gate
// rows. W: kf0-1 from LDS (staged once); kf2-7 streamed from L2 every step
// through a depth-2 two-slot register pipeline (wbuf[2][8], 64 VGPRs, issued
// 2 k-iters ahead). hA double-buffered, one barrier/step. xp preloaded at
// step top (xv[4], 16 regs), consumed in cell phase.
__global__ __launch_bounds__(512, 2) void lstm_rec2(
    const u16* __restrict__ xp0, const u16* __restrict__ xp1,
    const u16* __restrict__ W0,  const u16* __restrict__ W1,
    u16* __restrict__ h0c, float* __restrict__ hlast,
    u16* __restrict__ hs0, float* __restrict__ cs0,
    u16* __restrict__ hs1, float* __restrict__ cs1, int it)
{
    const int L   = blockIdx.x >> 4;
    const int blk = blockIdx.x & 15;
    if (L == 0 && it >= NCH) return;
    if (L == 1 && it == 0) return;
    const int chunk = L ? it - 1 : it;
    const u16* xp = L ? xp1 : xp0;
    const u16* W  = L ? W1 : W0;
    u16*  hs = L ? hs1 : hs0;
    float* cs = L ? cs1 : cs0;
    const int init = (chunk == 0);

    __shared__ __align__(16) u16 WL[8 * 16 * 64 * 8];   // 131072 B: kf0-1, frag-order
    __shared__ __align__(16) u16 hA[2][16][264];        // 16896 B, double buffer

    const int tid  = threadIdx.x;
    const int wave = tid >> 6, lane = tid & 63;
    const int ml   = lane & 15, q = lane >> 4;
    const int ub   = wave * 32;
    const int bb0  = blk * 16;

    // W fragment element offsets: frag f = gi*2+s -> gate rows g
    int woff_[8];
    #pragma unroll
    for (int gi = 0; gi < 4; ++gi)
        #pragma unroll
        for (int s = 0; s < 2; ++s)
            woff_[gi * 2 + s] = (gi * 256 + ub + s * 16 + ml) * 256 + q * 8;

    // stage kf0-1 into LDS (lane round-trips its own 16 B; per-wave region,
    // no cross-wave readers -> no barrier needed for WL itself)
    const int wlb = (wave * 1024 + lane) * 8;
    #pragma unroll
    for (int kf = 0; kf < 2; ++kf)
        #pragma unroll
        for (int f = 0; f < 8; ++f)
            *(bf16x8*)&WL[wlb + (kf * 8 + f) * 512] =
                *(const bf16x8*)(W + woff_[f] + kf * 32);

    float c_[8];
    if (init) {
        for (int i = tid; i < 16 * 264; i += 512) ((u16*)&hA[0][0][0])[i] = 0;
        #pragma unroll
        for (int i = 0; i < 8; ++i) c_[i] = 0.f;
    } else {
        int m = tid >> 5, j0 = (tid & 31) * 8;
        *(bf16x8*)&hA[0][m][j0] = *(const bf16x8*)&hs[(size_t)(bb0 + m) * 256 + j0];
        #pragma unroll
        for (int s = 0; s < 2; ++s)
            #pragma unroll
            for (int r = 0; r < 4; ++r)
                c_[s * 4 + r] = cs[(size_t)(bb0 + q * 4 + r) * 256 + ub + s * 16 + ml];
    }

    const u16* xpt = xp + ((size_t)blk * 512 + tid) * 32;   // advance XPSTEP/step

    __syncthreads();

    for (int t = 0; t < TCH; ++t) {
        const int br = t & 1, bw = br ^ 1;

        // xp for this step: 4x16B, in flight across the whole K-loop
        bf16x8 xv[4];
        #pragma unroll
        for (int j = 0; j < 4; ++j)
            xv[j] = *(const bf16x8*)(xpt + j * 8);

        // W stream prologue: kf2 -> wbuf[0], kf3 -> wbuf[1]
        bf16x8 wbuf[2][8];
        #pragma unroll
        for (int f = 0; f < 8; ++f)
            wbuf[0][f] = *(const bf16x8*)(W + woff_[f] + 2 * 32);
        #pragma unroll
        for (int f = 0; f < 8; ++f)
            wbuf[1][f] = *(const bf16x8*)(W + woff_[f] + 3 * 32);

        f32x4 acc[4][2];
        #pragma unroll
        for (int gi = 0; gi < 4; ++gi)
            #pragma unroll
            for (int s = 0; s < 2; ++s)
                acc[gi][s] = (f32x4)0.f;

        // kf0-1 from LDS (covers the wbuf prologue's L2 latency)
        #pragma unroll
        for (int kf = 0; kf < 2; ++kf) {
            bf16x8 a = *(const bf16x8*)&hA[br][ml][kf * 32 + q * 8];
            #pragma unroll
            for (int f = 0; f < 8; ++f) {
                bf16x8 b = *(const bf16x8*)&WL[wlb + (kf * 8 + f) * 512];
                acc[f >> 1][f & 1] = __builtin_amdgcn_mfma_f32_16x16x32_bf16(
                    a, b, acc[f >> 1][f & 1], 0, 0, 0);
            }
        }
        // kf2-7: consume wbuf[k&1], then refill it for k+2
        #pragma unroll
        for (int k = 2; k < 8; ++k) {
            bf16x8 a = *(const bf16x8*)&hA[br][ml][k * 32 + q * 8];
            #pragma unroll
            for (int f = 0; f < 8; ++f)
                acc[f >> 1][f & 1] = __builtin_amdgcn_mfma_f32_16x16x32_bf16(
                    a, wbuf[k & 1][f], acc[f >> 1][f & 1], 0, 0, 0);
            if (k < 6) {
                #pragma unroll
                for (int f = 0; f < 8; ++f)
                    wbuf[k & 1][f] = *(const bf16x8*)(W + woff_[f] + (k + 2) * 32);
            }
        }

        // cell phase: pre-activation = acc + xp (bias folded into xp).
        // xp micro-layout (s,r)-major: element (s*4+r)*4+gi -> xv[u>>1][(u&1)*4+gi]
        #pragma unroll
        for (int s = 0; s < 2; ++s) {
            int j = ub + s * 16 + ml;
            #pragma unroll
            for (int r = 0; r < 4; ++r) {
                int m = q * 4 + r;
                int u = s * 4 + r;
                int hi = (u & 1) * 4;
                float ig = sigm(acc[0][s][r] + bf2f((u16)xv[u >> 1][hi + 0]));
                float fg = sigm(acc[1][s][r] + bf2f((u16)xv[u >> 1][hi + 1]));
                float gg = tanh_f(acc[2][s][r] + bf2f((u16)xv[u >> 1][hi + 2]));
                float og = sigm(acc[3][s][r] + bf2f((u16)xv[u >> 1][hi + 3]));
                float cc = fg * c_[s * 4 + r] + ig * gg;
                c_[s * 4 + r] = cc;
                float h = og * tanh_f(cc);
                u16 hb = f2bf(h);
                hA[bw][m][j] = hb;
                if (L == 0)
                    h0c[((size_t)t * 256 + bb0 + m) * 256 + j] = hb;
                else if (chunk == NCH - 1 && t == TCH - 1)
                    hlast[(size_t)(bb0 + m) * 256 + j] = h;
            }
        }
        xpt += XPSTEP;
        __syncthreads();   // h(t+1) published in buf bw
    }

    // persist state (TCH even -> final h in buf 0)
    #pragma unroll
    for (int s = 0; s < 2; ++s)
        #pragma unroll
        for (int r = 0; r < 4; ++r)
            cs[(size_t)(bb0 + q * 4 + r) * 256 + ub + s * 16 + ml] = c_[s * 4 + r];
    {
        int m = tid >> 5, j0 = (tid & 31) * 8;
        *(bf16x8*)&hs[(size_t)(bb0 + m) * 256 + j0] = *(const bf16x8*)&hA[0][m][j0];
    }
}

// ---------------- FC head ----------------
__global__ void fc_k(const float* __restrict__ h, const float* __restrict__ w,
                     const float* __restrict__ b, float* __restrict__ out)
{
    int bb = blockIdx.x, lane = threadIdx.x;
    float s = 0.f;
    for (int j = lane; j < 256; j += 64) s += h[bb * 256 + j] * w[j];
    #pragma unroll
    for (int off = 32; off > 0; off >>= 1) s += __shfl_down(s, off);
    if (lane == 0) out[bb] = s + b[0];
}

extern "C" void kernel_launch(void* const* d_in, const int* in_sizes, int n_in,
                              void* d_out, int out_size, void* d_ws, size_t ws_size,
                              hipStream_t stream)
{
    const float* x    = (const float*)d_in[0];
    const float* Wih0 = (const float*)d_in[1];
    const float* Whh0 = (const float*)d_in[2];
    const float* bih0 = (const float*)d_in[3];
    const float* bhh0 = (const float*)d_in[4];
    const float* Wih1 = (const float*)d_in[5];
    const float* Whh1 = (const float*)d_in[6];
    const float* bih1 = (const float*)d_in[7];
    const float* bhh1 = (const float*)d_in[8];
    const float* fcw  = (const float*)d_in[9];
    const float* fcb  = (const float*)d_in[10];
    float* out = (float*)d_out;

    // workspace layout, total ~57.3 MB
    char* ws = (char*)d_ws;
    u16*   xp0   = (u16*)(ws);                  // 16777216
    u16*   xp1   = (u16*)(ws + 16777216);       // 16777216
    u16*   h0c   = (u16*)(ws + 33554432);       //  4194304  [32][256][256] bf16
    u16*   xb    = (u16*)(ws + 37748736);       // 16777216  [256][512][64] bf16
    u16*   Wih0b = (u16*)(ws + 54525952);       //   131072
    u16*   Whh0b = (u16*)(ws + 54657024);       //   524288
    u16*   Wih1b = (u16*)(ws + 55181312);       //   524288
    u16*   Whh1b = (u16*)(ws + 55705600);       //   524288
    float* bias0 = (float*)(ws + 56229888);     //     4096
    float* bias1 = (float*)(ws + 56233984);     //     4096
    u16*   hs0   = (u16*)(ws + 56238080);       //   131072
    float* cs0   = (float*)(ws + 56369152);     //   262144
    u16*   hs1   = (u16*)(ws + 56631296);       //   131072
    float* cs1   = (float*)(ws + 56762368);     //   262144
    float* h1l   = (float*)(ws + 57024512);     //   262144

    k_conv<<<32768, 256, 0, stream>>>(x, xb, 8388608);
    k_conv<<<256,   256, 0, stream>>>(Wih0, Wih0b, 65536);
    k_conv<<<1024,  256, 0, stream>>>(Whh0, Whh0b, 262144);
    k_conv<<<1024,  256, 0, stream>>>(Wih1, Wih1b, 262144);
    k_conv<<<1024,  256, 0, stream>>>(Whh1, Whh1b, 262144);
    k_bias<<<4, 256, 0, stream>>>(bih0, bhh0, bias0, 1024);
    k_bias<<<4, 256, 0, stream>>>(bih1, bhh1, bias1, 1024);

    for (int it = 0; it <= NCH; ++it) {
        gemm_fused<<<1024, 256, 0, stream>>>(xb, Wih0b, bias0, xp0, it * TCH,
                                             h0c, Wih1b, bias1, xp1, it);
        lstm_rec2<<<32, 512, 0, stream>>>(xp0, xp1, Whh0b, Whh1b, h0c, h1l,
                                          hs0, cs0, hs1, cs1, it);
    }
    fc_k<<<256, 64, 0, stream>>>(h1l, fcw, fcb, out);
}